// Round 7
// baseline (1304.901 us; speedup 1.0000x reference)
//
#include <hip/hip_runtime.h>
#include <math.h>

#define HID 128
#define NLAYERS 4
#define NGRAPHS 200
#define NCLASSES 10
#define BN_EPS 1e-5f

typedef short bf16x8 __attribute__((ext_vector_type(8)));
typedef float f32x4 __attribute__((ext_vector_type(4)));

__device__ __forceinline__ ushort f2bf(float f) {
    unsigned u = __float_as_uint(f);
    u = (u + 0x7fffu + ((u >> 16) & 1u)) >> 16;
    return (ushort)u;
}
__device__ __forceinline__ float bf2f(unsigned us) { return __uint_as_float(us << 16); }

// ---------------- prep kernels ----------------

// H0 = bf16(x)
__global__ void k_init_x(const float* __restrict__ x, ushort* __restrict__ H0, int N) {
    int idx = blockIdx.x * blockDim.x + threadIdx.x;
    if (idx < N * HID) H0[idx] = f2bf(x[idx]);
}

// C[l][k][j] = sum_o W_l[k][o] * w_ih[j][o]   (fp32, composed message+input weights)
__global__ __launch_bounds__(128) void k_wgemm(const float* __restrict__ W,
                                               const float* __restrict__ w_ih,
                                               float* __restrict__ C) {
    int l = blockIdx.x >> 7, k = blockIdx.x & 127;
    __shared__ float wrow[128];
    wrow[threadIdx.x] = W[(l << 14) + k * 128 + threadIdx.x];
    __syncthreads();
    for (int j = threadIdx.x; j < 384; j += 128) {
        float acc = 0.f;
#pragma unroll 4
        for (int o = 0; o < 128; ++o) acc += wrow[o] * w_ih[j * 128 + o];
        C[((size_t)l * 128 + k) * 384 + j] = acc;
    }
}

// Per-layer combined GRU weights in MFMA-fragment order (K=256 over [s|h], 512 outs)
__global__ void k_build_Bc(const float* __restrict__ C, const float* __restrict__ w_hh,
                           ushort* __restrict__ Bc2) {
    int idx = blockIdx.x * blockDim.x + threadIdx.x;
    if (idx >= NLAYERS * 512 * 256) return;
    int jf = idx & 7, lane = (idx >> 3) & 63, ks = (idx >> 9) & 7, ct = (idx >> 12) & 31;
    int l = idx >> 17;
    int o = ct * 16 + (lane & 15);
    int k = ks * 32 + (lane >> 4) * 8 + jf;
    float v;
    if (k < 128)      v = (o < 384) ? C[((size_t)l * 128 + k) * 384 + o] : 0.f;
    else if (o < 256) v = w_hh[o * 128 + (k - 128)];
    else if (o < 384) v = 0.f;
    else              v = w_hh[(o - 128) * 128 + (k - 128)];
    Bc2[idx] = f2bf(v);
}

__global__ void k_bias(const float* __restrict__ b_ih, const float* __restrict__ b_hh,
                       float* __restrict__ bias) {
    int j = threadIdx.x;
    if (j >= 512) return;
    float v;
    if (j < 256)      v = b_ih[j] + b_hh[j];
    else if (j < 384) v = b_ih[j];
    else              v = b_hh[j - 128];
    bias[j] = v;
}

// fc1_w[o][k] -> fragment order (K=128: ks in [0,4), ct in [0,8))
__global__ void k_cvt_fc1(const float* __restrict__ w, ushort* __restrict__ B2) {
    int idx = blockIdx.x * blockDim.x + threadIdx.x;
    if (idx >= 16384) return;
    int j = idx & 7, lane = (idx >> 3) & 63, ks = (idx >> 9) & 3, ct = idx >> 11;
    int o = ct * 16 + (lane & 15);
    int k = ks * 32 + (lane >> 4) * 8 + j;
    B2[idx] = f2bf(w[o * 128 + k]);
}

// ---------------- CSR build (direct fill) ----------------

__global__ void k_deg(const int* __restrict__ ei, int E, int* __restrict__ deg) {
    int e = blockIdx.x * blockDim.x + threadIdx.x;
    if (e < E) atomicAdd(&deg[ei[E + e]], 1);
}

__global__ void k_scan1(const int* __restrict__ deg, int N,
                        int* __restrict__ rowstart, int* __restrict__ bsum) {
    __shared__ int s[256];
    int t = threadIdx.x;
    int i = blockIdx.x * 256 + t;
    int v = (i < N) ? deg[i] : 0;
    s[t] = v;
    __syncthreads();
    for (int off = 1; off < 256; off <<= 1) {
        int a = (t >= off) ? s[t - off] : 0;
        __syncthreads();
        s[t] += a;
        __syncthreads();
    }
    if (i < N) rowstart[i] = s[t] - v;
    if (t == 255) bsum[blockIdx.x] = s[255];
}

__global__ void k_scan2(const int* __restrict__ bsum, int nb, int* __restrict__ boff) {
    __shared__ int s[512];
    int t = threadIdx.x;
    int v = (t < nb) ? bsum[t] : 0;
    s[t] = v;
    __syncthreads();
    for (int off = 1; off < 512; off <<= 1) {
        int a = (t >= off) ? s[t - off] : 0;
        __syncthreads();
        s[t] += a;
        __syncthreads();
    }
    if (t < nb) boff[t] = s[t] - v;
}

__global__ void k_scan3(int* __restrict__ rowstart, const int* __restrict__ boff,
                        int N, int E) {
    int i = blockIdx.x * 256 + threadIdx.x;
    if (i < N) rowstart[i] += boff[blockIdx.x];
    if (i == 0) rowstart[N] = E;
}

__global__ void k_fill(const int* __restrict__ ei, int E,
                       const int* __restrict__ rowstart, int* __restrict__ cursor,
                       int* __restrict__ col) {
    int e = blockIdx.x * blockDim.x + threadIdx.x;
    if (e < E) {
        int d = ei[E + e];
        int pos = atomicAdd(&cursor[d], 1);
        col[rowstart[d] + pos] = ei[e];
    }
}

// ---------------- graph segment starts (batch is sorted) ----------------

__global__ void k_gstart(const int* __restrict__ batch, int* __restrict__ gstart, int N) {
    int n = blockIdx.x * blockDim.x + threadIdx.x;
    if (n > N) return;
    int curb = (n == N) ? NGRAPHS : batch[n];
    int prev = (n == 0) ? -1 : batch[n - 1];
    for (int g = prev + 1; g <= curb; ++g) gstart[g] = n;
}

// ---------------- fused layer: gather s -> LDS, GEMM, GRU gates, Hnew ----------------
// Tile = 64 nodes. Phase 1: stage h-half from Hold (sequential) + gather s-half
// (random 256B row reads of Hold). Phase 2: C[64,512] = As[64,256]@Bc^T with gate
// epilogue; old h read back from LDS; only Hnew (bf16) written to global.

#define LDA 264
__global__ __launch_bounds__(256, 2) void k_layer(
    const int* __restrict__ rowstart, const int* __restrict__ col,
    const ushort* __restrict__ Hold, const ushort* __restrict__ Bc2,
    const float* __restrict__ bias, ushort* __restrict__ Hnew, int N) {
    __shared__ ushort As[64 * LDA];
    int t = threadIdx.x;
    int rowb = blockIdx.x << 6;
    int w = t >> 6, lane = t & 63;
    int sub = lane >> 4, chunk = lane & 15;

    // stage h-half: As[r][128:256] = Hold[rowb+r]
    for (int c = t; c < 1024; c += 256) {
        int r = c >> 4, off = (c & 15) * 8;
        int node = rowb + r;
        bf16x8 v = (bf16x8){0, 0, 0, 0, 0, 0, 0, 0};
        if (node < N) v = *(const bf16x8*)(Hold + (size_t)node * 128 + off);
        *(bf16x8*)(As + r * LDA + 128 + off) = v;
    }
    // gather s-half: wave w handles nodes rowb + w*16 .. +15
    for (int i = 0; i < 16; ++i) {
        int local = w * 16 + i;
        int node = rowb + local;
        float acc[8];
#pragma unroll
        for (int k = 0; k < 8; ++k) acc[k] = 0.f;
        if (node < N) {
            int s = rowstart[node], e = rowstart[node + 1];
            int idx = s + sub;
            for (; idx + 12 < e; idx += 16) {
                int c0 = col[idx], c1 = col[idx + 4], c2 = col[idx + 8], c3 = col[idx + 12];
                bf16x8 v0 = *(const bf16x8*)(Hold + (size_t)c0 * 128 + chunk * 8);
                bf16x8 v1 = *(const bf16x8*)(Hold + (size_t)c1 * 128 + chunk * 8);
                bf16x8 v2 = *(const bf16x8*)(Hold + (size_t)c2 * 128 + chunk * 8);
                bf16x8 v3 = *(const bf16x8*)(Hold + (size_t)c3 * 128 + chunk * 8);
#pragma unroll
                for (int k = 0; k < 8; ++k) {
                    acc[k] += bf2f((ushort)v0[k]) + bf2f((ushort)v1[k]);
                    acc[k] += bf2f((ushort)v2[k]) + bf2f((ushort)v3[k]);
                }
            }
            for (; idx < e; idx += 4) {
                int c0 = col[idx];
                bf16x8 v0 = *(const bf16x8*)(Hold + (size_t)c0 * 128 + chunk * 8);
#pragma unroll
                for (int k = 0; k < 8; ++k) acc[k] += bf2f((ushort)v0[k]);
            }
        }
#pragma unroll
        for (int k = 0; k < 8; ++k) {
            acc[k] += __shfl_xor(acc[k], 16);
            acc[k] += __shfl_xor(acc[k], 32);
        }
        if (sub == 0) {
            union { ushort u[8]; bf16x8 v; } o;
#pragma unroll
            for (int k = 0; k < 8; ++k) o.u[k] = f2bf(acc[k]);
            *(bf16x8*)(As + local * LDA + chunk * 8) = o.v;
        }
    }
    __syncthreads();

    int quad = lane >> 4, tn = lane & 15;
    f32x4 acc[4][4][2]; // [row-tile][gate-group][col-half]
#pragma unroll
    for (int rt = 0; rt < 4; ++rt)
#pragma unroll
        for (int g = 0; g < 4; ++g)
#pragma unroll
            for (int c2 = 0; c2 < 2; ++c2) acc[rt][g][c2] = (f32x4){0.f, 0.f, 0.f, 0.f};
    for (int ks = 0; ks < 8; ++ks) {
        int k0 = ks * 32 + quad * 8;
        bf16x8 bfr[4][2];
#pragma unroll
        for (int g = 0; g < 4; ++g)
#pragma unroll
            for (int c2 = 0; c2 < 2; ++c2) {
                int ct = g * 8 + w * 2 + c2;
                bfr[g][c2] = *(const bf16x8*)(Bc2 + (size_t)((ct * 8 + ks) * 64 + lane) * 8);
            }
        bf16x8 af[4];
#pragma unroll
        for (int rt = 0; rt < 4; ++rt)
            af[rt] = *(const bf16x8*)(As + (rt * 16 + tn) * LDA + k0);
#pragma unroll
        for (int rt = 0; rt < 4; ++rt)
#pragma unroll
            for (int g = 0; g < 4; ++g)
#pragma unroll
                for (int c2 = 0; c2 < 2; ++c2)
                    acc[rt][g][c2] = __builtin_amdgcn_mfma_f32_16x16x32_bf16(
                        af[rt], bfr[g][c2], acc[rt][g][c2], 0, 0, 0);
    }
#pragma unroll
    for (int c2 = 0; c2 < 2; ++c2) {
        int cc = w * 32 + c2 * 16 + tn;
        float br = bias[cc], bz = bias[128 + cc], bin = bias[256 + cc], bhn = bias[384 + cc];
#pragma unroll
        for (int rt = 0; rt < 4; ++rt)
#pragma unroll
            for (int r = 0; r < 4; ++r) {
                int rl = rt * 16 + quad * 4 + r;
                int row = rowb + rl;
                float ur = acc[rt][0][c2][r] + br;
                float uz = acc[rt][1][c2][r] + bz;
                float xin = acc[rt][2][c2][r] + bin;
                float xhn = acc[rt][3][c2][r] + bhn;
                float rr = 1.f / (1.f + __expf(-ur));
                float zz = 1.f / (1.f + __expf(-uz));
                float xt = xin + rr * xhn;
                float ex = __expf(2.f * fminf(fmaxf(xt, -15.f), 15.f));
                float nn = (ex - 1.f) / (ex + 1.f);
                float ho = bf2f(As[rl * LDA + 128 + cc]);
                float hv = (1.f - zz) * nn + zz * ho;
                if (row < N) Hnew[(size_t)row * 128 + cc] = f2bf(hv);
            }
    }
}

// ---------------- MFMA GEMM (fc1): y[P,128] = H@B ----------

#define LDA2 136
__global__ __launch_bounds__(256, 2) void k_mm_mfma(
    const ushort* __restrict__ Ain, const ushort* __restrict__ B2,
    ushort* __restrict__ mo, int N) {
    __shared__ ushort As[64 * LDA2];
    int t = threadIdx.x;
    int rowb = blockIdx.x << 6;
    for (int c = t; c < 1024; c += 256) {
        int r = c >> 4, off = (c & 15) * 8;
        int node = rowb + r;
        bf16x8 v = (bf16x8){0, 0, 0, 0, 0, 0, 0, 0};
        if (node < N) v = *(const bf16x8*)(Ain + (size_t)node * 128 + off);
        *(bf16x8*)(As + r * LDA2 + off) = v;
    }
    __syncthreads();
    int w = t >> 6, lane = t & 63;
    int quad = lane >> 4, tn = lane & 15;
    f32x4 acc[4][2];
#pragma unroll
    for (int rt = 0; rt < 4; ++rt)
#pragma unroll
        for (int c2 = 0; c2 < 2; ++c2) acc[rt][c2] = (f32x4){0.f, 0.f, 0.f, 0.f};
    for (int ks = 0; ks < 4; ++ks) {
        int k0 = ks * 32 + quad * 8;
        bf16x8 bfr[2];
#pragma unroll
        for (int c2 = 0; c2 < 2; ++c2) {
            int ct = w * 2 + c2;
            bfr[c2] = *(const bf16x8*)(B2 + (size_t)((ct * 4 + ks) * 64 + lane) * 8);
        }
        bf16x8 af[4];
#pragma unroll
        for (int rt = 0; rt < 4; ++rt)
            af[rt] = *(const bf16x8*)(As + (rt * 16 + tn) * LDA2 + k0);
#pragma unroll
        for (int rt = 0; rt < 4; ++rt)
#pragma unroll
            for (int c2 = 0; c2 < 2; ++c2)
                acc[rt][c2] = __builtin_amdgcn_mfma_f32_16x16x32_bf16(
                    af[rt], bfr[c2], acc[rt][c2], 0, 0, 0);
    }
#pragma unroll
    for (int c2 = 0; c2 < 2; ++c2) {
        int col = w * 32 + c2 * 16 + tn;
#pragma unroll
        for (int rt = 0; rt < 4; ++rt)
#pragma unroll
            for (int r = 0; r < 4; ++r) {
                int row = rowb + rt * 16 + quad * 4 + r;
                mo[row * 128 + col] = f2bf(acc[rt][c2][r]);
            }
    }
}

// ---------------- BN stats / finalize / pool / head ----------------

__global__ __launch_bounds__(256) void k_bnstats(const ushort* __restrict__ y,
                                                 float* __restrict__ stats, int N) {
    int half = threadIdx.x >> 7, f = threadIdx.x & 127;
    float s = 0.f, s2 = 0.f;
    for (int n = blockIdx.x * 2 + half; n < N; n += gridDim.x * 2) {
        float v = bf2f(y[n * HID + f]);
        s += v;
        s2 += v * v;
    }
    __shared__ float ls[2][HID], ls2[2][HID];
    ls[half][f] = s;
    ls2[half][f] = s2;
    __syncthreads();
    if (half == 0) {
        atomicAdd(&stats[f], ls[0][f] + ls[1][f]);
        atomicAdd(&stats[HID + f], ls2[0][f] + ls2[1][f]);
    }
}

__global__ void k_bnfinal(float* __restrict__ stats, const float* __restrict__ gamma,
                          const float* __restrict__ beta, float n) {
    int j = threadIdx.x;
    if (j < HID) {
        float mu = stats[j] / n;
        float var = stats[HID + j] / n - mu * mu;
        float sc = gamma[j] * rsqrtf(var + BN_EPS);
        stats[256 + j] = sc;
        stats[384 + j] = beta[j] - mu * sc;
    }
}

// atomic-light pool: block = (graph, quarter), rows contiguous via gstart
__global__ __launch_bounds__(256) void k_pool(const ushort* __restrict__ y,
                                              const float* __restrict__ stats,
                                              const int* __restrict__ gstart,
                                              float* __restrict__ gsum) {
    int g = blockIdx.x >> 2, q = blockIdx.x & 3;
    int f = threadIdx.x & 127, half = threadIdx.x >> 7;
    int gs = gstart[g], ge = gstart[g + 1];
    int len = ge - gs;
    int r0 = gs + ((len * q) >> 2), r1 = gs + ((len * (q + 1)) >> 2);
    float sc = stats[256 + f], sh = stats[384 + f];
    float acc = 0.f;
    for (int n = r0 + half; n < r1; n += 2)
        acc += fmaxf(bf2f(y[n * HID + f]) * sc + sh, 0.f);
    __shared__ float ls[2][HID];
    ls[half][f] = acc;
    __syncthreads();
    if (half == 0) atomicAdd(&gsum[g * HID + f], ls[0][f] + ls[1][f]);
}

__global__ void k_head(const float* __restrict__ gsum, const int* __restrict__ gstart,
                       const float* __restrict__ w2, const float* __restrict__ b2,
                       float* __restrict__ out) {
    int g = blockIdx.x * blockDim.x + threadIdx.x;
    if (g >= NGRAPHS) return;
    float cnt = (float)(gstart[g + 1] - gstart[g]);
    float inv = 1.0f / fmaxf(cnt, 1.0f);
    float logits[NCLASSES];
    float mx = -1e30f;
    for (int c = 0; c < NCLASSES; ++c) {
        float acc = b2[c];
        for (int f = 0; f < HID; ++f) acc += gsum[g * HID + f] * inv * w2[c * HID + f];
        logits[c] = acc;
        mx = fmaxf(mx, acc);
    }
    float se = 0.f;
    for (int c = 0; c < NCLASSES; ++c) se += expf(logits[c] - mx);
    float lse = mx + logf(se);
    for (int c = 0; c < NCLASSES; ++c) out[g * NCLASSES + c] = logits[c] - lse;
}

// ---------------- launch ----------------

extern "C" void kernel_launch(void* const* d_in, const int* in_sizes, int n_in,
                              void* d_out, int out_size, void* d_ws, size_t ws_size,
                              hipStream_t stream) {
    const float* x     = (const float*)d_in[0];
    const int*   ei    = (const int*)d_in[1];
    const int*   batch = (const int*)d_in[2];
    const float* ggnnw = (const float*)d_in[3];
    const float* w_ih  = (const float*)d_in[4];
    const float* w_hh  = (const float*)d_in[5];
    const float* b_ih  = (const float*)d_in[6];
    const float* b_hh  = (const float*)d_in[7];
    const float* fc1_w = (const float*)d_in[8];
    // d_in[9] fc1_b: cancels exactly in training-mode BN -> unused
    const float* gamma = (const float*)d_in[10];
    const float* beta  = (const float*)d_in[11];
    const float* fc2_w = (const float*)d_in[12];
    const float* fc2_b = (const float*)d_in[13];
    float* out = (float*)d_out;

    const int N = in_sizes[0] / HID; // 100000
    const int E = in_sizes[1] / 2;   // 1600000
    const int nblk64 = (N + 63) / 64;
    const int P = nblk64 * 64;

    char* w = (char*)d_ws;
    auto alloc = [&](size_t bytes) -> char* {
        char* p = w;
        w += (bytes + 255) & ~(size_t)255;
        return p;
    };
    ushort* H0  = (ushort*)alloc(sizeof(ushort) * (size_t)P * HID); // h state (bf16), buf 0
    ushort* H1  = (ushort*)alloc(sizeof(ushort) * (size_t)P * HID); // h state (bf16), buf 1
    ushort* y   = (ushort*)alloc(sizeof(ushort) * (size_t)P * HID); // fc1 output
    ushort* Bc2 = (ushort*)alloc(sizeof(ushort) * NLAYERS * 512 * 256);
    float*  C   = (float*)alloc(sizeof(float) * NLAYERS * 128 * 384);
    ushort* f1b = (ushort*)alloc(sizeof(ushort) * HID * HID);
    float*  bias = (float*)alloc(sizeof(float) * 512);
    int* rowstart = (int*)alloc(sizeof(int) * (N + 4));
    int* colb     = (int*)alloc(sizeof(int) * E);
    int* bsum     = (int*)alloc(sizeof(int) * 512);
    int* boff     = (int*)alloc(sizeof(int) * 512);
    int* gstart   = (int*)alloc(sizeof(int) * (NGRAPHS + 4));
    // zero-initialized region: deg, cursor, stats, gsum
    size_t zelems = (size_t)N + N + 512 + NGRAPHS * HID;
    char* zbase = alloc(zelems * 4);
    int*   deg    = (int*)zbase;
    int*   cursor = deg + N;
    float* stats  = (float*)(cursor + N);
    float* gsum   = stats + 512;

    hipMemsetAsync(zbase, 0, zelems * 4, stream);

    k_init_x<<<(N * HID + 255) / 256, 256, 0, stream>>>(x, H0, N);
    k_wgemm<<<NLAYERS * 128, 128, 0, stream>>>(ggnnw, w_ih, C);
    k_build_Bc<<<(NLAYERS * 512 * 256 + 255) / 256, 256, 0, stream>>>(C, w_hh, Bc2);
    k_bias<<<1, 512, 0, stream>>>(b_ih, b_hh, bias);
    k_cvt_fc1<<<(16384 + 255) / 256, 256, 0, stream>>>(fc1_w, f1b);

    // CSR build (direct fill)
    int nb1 = (N + 255) / 256;
    k_deg<<<(E + 255) / 256, 256, 0, stream>>>(ei, E, deg);
    k_scan1<<<nb1, 256, 0, stream>>>(deg, N, rowstart, bsum);
    k_scan2<<<1, 512, 0, stream>>>(bsum, nb1, boff);
    k_scan3<<<nb1, 256, 0, stream>>>(rowstart, boff, N, E);
    k_fill<<<(E + 255) / 256, 256, 0, stream>>>(ei, E, rowstart, cursor, colb);
    k_gstart<<<(N + 256) / 256, 256, 0, stream>>>(batch, gstart, N);

    ushort* Hbuf[2] = {H0, H1};
    for (int l = 0; l < NLAYERS; ++l) {
        k_layer<<<nblk64, 256, 0, stream>>>(rowstart, colb, Hbuf[l & 1],
                                            Bc2 + (size_t)l * 512 * 256, bias,
                                            Hbuf[(l + 1) & 1], N);
    }
    ushort* Hfin = Hbuf[NLAYERS & 1];

    // head: fc1 (bias cancels in BN) -> BN -> relu -> pool -> fc2 -> log_softmax
    k_mm_mfma<<<nblk64, 256, 0, stream>>>(Hfin, f1b, y, N);
    k_bnstats<<<512, 256, 0, stream>>>(y, stats, N);
    k_bnfinal<<<1, 128, 0, stream>>>(stats, gamma, beta, (float)N);
    k_pool<<<NGRAPHS * 4, 256, 0, stream>>>(y, stats, gstart, gsum);
    k_head<<<1, 256, 0, stream>>>(gsum, gstart, fc2_w, fc2_b, out);
}